// Round 7
// baseline (197.820 us; speedup 1.0000x reference)
//
#include <hip/hip_runtime.h>

typedef float v2f __attribute__((ext_vector_type(2)));
typedef float v4f __attribute__((ext_vector_type(4)));

#define EPS 1e-7f
#define SPW 66   // LDS row stride in v2f: 528 B = 33*16 (even pairs stay b128-aligned)

// mantissa_map: (|v|+eps) -> mantissa m in [1,2); result = m>=1.5 ? m/2 : m  -> [0.75,1.5)
__device__ __forceinline__ float mant_map(float v) {
    float a = fabsf(v) + EPS;
    unsigned int bi = __float_as_uint(a);
    float m = __uint_as_float((bi & 0x007FFFFFu) | 0x3F800000u);
    return (m >= 1.5f) ? 0.5f * m : m;
}

// R7: latency-pipelined phases. Grid (192,4,7), block (32,2)=64 thr = 1 wave.
// Block (c,b,z): output rows y0=8z..y0+7. Thread (lx,ty): out cols {2lx,2lx+1}
// (lx clamped to 27, store-guarded), out rows 4ty..4ty+3 -> 4-row register
// rotation over 10 LDS input rows.
// out = sum_taps u*B + v*C, u=x, v=x/M1, B=w/M2, C=B*(M2-1).
//
// R0-R6 lesson: time (~28-30us) is invariant to occupancy (12 vs 32 waves/CU)
// and to LDS instruction count; no pipe >40% busy -> per-wave lgkmcnt chains
// (weights+rows loaded at each phase start) dominate. R7: weight double-buffer
// (load phase i+1's 7 ds_read_b64 BEFORE phase i's 56 pk_fma) + row prefetch
// into the just-freed buffer AFTER them; 1-wave blocks make __syncthreads free
// so no cross-wave phase lockstep.
__global__ __launch_bounds__(64, 3) void wconv_kernel(const float* __restrict__ x,
                                                      const float* __restrict__ w,
                                                      float* __restrict__ out) {
    __shared__ v2f sp[14][SPW];  // LDS row r = input row y0-3+r; pair k = input col k-3
    __shared__ v2f swt[49];      // {B, C} per tap

    const int lx = threadIdx.x;   // 0..31
    const int ty = threadIdx.y;   // 0..1
    const int tid = ty * 32 + lx; // 0..63
    const int c = blockIdx.x;
    const int b = blockIdx.y;
    const int y0 = blockIdx.z * 8;

    const long plane = (long)(b * 192 + c) * 3136;
    const float* xp = x + plane;

    // --- fused weight prep ---
    if (tid < 49) {
        float wv = w[c * 49 + tid];
        float M2 = mant_map(wv);
        float B = wv / M2;
        swt[tid] = (v2f){B, B * (M2 - 1.0f)};
    }

    // --- side halo zero: pairs 0,1,2 (cols -3..-1) and 59,60,61 (cols 56..58) ---
    for (int t = tid; t < 84; t += 64) {
        int r = t / 6, k = t % 6;
        int col = (k < 3) ? k : 56 + k;
        sp[r][col] = (v2f){0.f, 0.f};
    }

    // --- interior staging: 14 rows x 14 quads = 196 tasks over 64 threads.
    // Rows outside the image (z=0: g<0, z=6: g>55) stage zeros. Loads first. ---
    {
        const int t0 = tid, t1 = tid + 64, t2 = tid + 128, t3 = tid + 192;
        const int r0 = t0 / 14, q0 = t0 % 14, g0 = y0 - 3 + r0;
        const int r1 = t1 / 14, q1 = t1 % 14, g1 = y0 - 3 + r1;
        const int r2 = t2 / 14, q2 = t2 % 14, g2 = y0 - 3 + r2;
        const int r3 = t3 / 14, q3 = t3 % 14, g3 = y0 - 3 + r3;

        v4f z4 = (v4f){0.f, 0.f, 0.f, 0.f};
        v4f u0 = z4, u1 = z4, u2 = z4, u3 = z4;
        if (g0 >= 0 && g0 < 56) u0 = *(const v4f*)(xp + g0 * 56 + q0 * 4);
        if (g1 >= 0 && g1 < 56) u1 = *(const v4f*)(xp + g1 * 56 + q1 * 4);
        if (g2 >= 0 && g2 < 56) u2 = *(const v4f*)(xp + g2 * 56 + q2 * 4);
        if (tid < 4 && g3 >= 0 && g3 < 56) u3 = *(const v4f*)(xp + g3 * 56 + q3 * 4);

        auto stage = [&](int r, int q, v4f u4) {
            v2f* dst = &sp[r][3 + q * 4];     // pairs 3+4q..6+4q = input cols 4q..4q+3
            dst[0] = (v2f){u4.x, u4.x * __builtin_amdgcn_rcpf(mant_map(u4.x))};
            dst[1] = (v2f){u4.y, u4.y * __builtin_amdgcn_rcpf(mant_map(u4.y))};
            dst[2] = (v2f){u4.z, u4.z * __builtin_amdgcn_rcpf(mant_map(u4.z))};
            dst[3] = (v2f){u4.w, u4.w * __builtin_amdgcn_rcpf(mant_map(u4.w))};
        };
        stage(r0, q0, u0);
        stage(r1, q1, u1);
        stage(r2, q2, u2);
        if (tid < 4) stage(r3, q3, u3);
    }
    __syncthreads();   // 1-wave block: compiles to a local waitcnt, no lockstep

    // --- compute: wave-uniform body (lanes 28..31 duplicate lane 27) ---
    {
        const int x0 = ((lx < 28) ? lx : 27) * 2;  // pair base; P[j] = input col 2lx-3+j
        const int rb = ty * 4;                     // out-row base; LDS rows rb..rb+9

        // row buffer: pairs x0..x0+7 of LDS row R (4x ds_read_b128, 16B-aligned)
#define LOADROW(P, R)                                                   \
        {                                                               \
            const v4f* s_ = (const v4f*)&sp[(R)][x0];                   \
            v4f t0_ = s_[0], t1_ = s_[1], t2_ = s_[2], t3_ = s_[3];     \
            P[0] = (v2f){t0_.x, t0_.y}; P[1] = (v2f){t0_.z, t0_.w};     \
            P[2] = (v2f){t1_.x, t1_.y}; P[3] = (v2f){t1_.z, t1_.w};     \
            P[4] = (v2f){t2_.x, t2_.y}; P[5] = (v2f){t2_.z, t2_.w};     \
            P[6] = (v2f){t3_.x, t3_.y}; P[7] = (v2f){t3_.z, t3_.w};     \
        }
#define LOADWT(W, I)                                                    \
        {                                                               \
            _Pragma("unroll")                                           \
            for (int j = 0; j < 7; ++j) W[j] = swt[(I) * 7 + j];        \
        }
        // phase: out row rb+k accumulates wt_row[i][j] * LDSrow[rb+i+k], row in Pk
#define PHASE(W, P0, P1, P2, P3)                                        \
        {                                                               \
            _Pragma("unroll")                                           \
            for (int j = 0; j < 7; ++j) {                               \
                v2f wc = W[j];                                          \
                a00 += P0[j] * wc;  a01 += P0[j + 1] * wc;              \
                a10 += P1[j] * wc;  a11 += P1[j + 1] * wc;              \
                a20 += P2[j] * wc;  a21 += P2[j + 1] * wc;              \
                a30 += P3[j] * wc;  a31 += P3[j + 1] * wc;              \
            }                                                           \
        }

        v2f b0[8], b1[8], b2[8], b3[8];
        v2f wta[7], wtb[7];
        v2f a00 = {0.f,0.f}, a01 = {0.f,0.f}, a10 = {0.f,0.f}, a11 = {0.f,0.f};
        v2f a20 = {0.f,0.f}, a21 = {0.f,0.f}, a30 = {0.f,0.f}, a31 = {0.f,0.f};

        LOADROW(b0, rb + 0) LOADROW(b1, rb + 1) LOADROW(b2, rb + 2) LOADROW(b3, rb + 3)
        LOADWT(wta, 0)
        // phase i: prefetch weights i+1; FMA with rows rb+i..rb+i+3; refill freed buf
        LOADWT(wtb, 1)  PHASE(wta, b0, b1, b2, b3)  LOADROW(b0, rb + 4)
        LOADWT(wta, 2)  PHASE(wtb, b1, b2, b3, b0)  LOADROW(b1, rb + 5)
        LOADWT(wtb, 3)  PHASE(wta, b2, b3, b0, b1)  LOADROW(b2, rb + 6)
        LOADWT(wta, 4)  PHASE(wtb, b3, b0, b1, b2)  LOADROW(b3, rb + 7)
        LOADWT(wtb, 5)  PHASE(wta, b0, b1, b2, b3)  LOADROW(b0, rb + 8)
        LOADWT(wta, 6)  PHASE(wtb, b1, b2, b3, b0)  LOADROW(b1, rb + 9)
                        PHASE(wta, b2, b3, b0, b1)
#undef PHASE
#undef LOADWT
#undef LOADROW

        // --- store: the only divergent region ---
        if (lx < 28) {
            float2 o0 = make_float2(a00.x + a00.y, a01.x + a01.y);
            float2 o1 = make_float2(a10.x + a10.y, a11.x + a11.y);
            float2 o2 = make_float2(a20.x + a20.y, a21.x + a21.y);
            float2 o3 = make_float2(a30.x + a30.y, a31.x + a31.y);
            *(float2*)&out[plane + (y0 + rb)     * 56 + x0] = o0;
            *(float2*)&out[plane + (y0 + rb + 1) * 56 + x0] = o1;
            *(float2*)&out[plane + (y0 + rb + 2) * 56 + x0] = o2;
            *(float2*)&out[plane + (y0 + rb + 3) * 56 + x0] = o3;
        }
    }
}

extern "C" void kernel_launch(void* const* d_in, const int* in_sizes, int n_in,
                              void* d_out, int out_size, void* d_ws, size_t ws_size,
                              hipStream_t stream) {
    const float* x = (const float*)d_in[0];   // (4,192,56,56) fp32
    const float* w = (const float*)d_in[1];   // (192,1,7,7) fp32
    float* out = (float*)d_out;

    hipLaunchKernelGGL(wconv_kernel, dim3(192, 4, 7), dim3(32, 2), 0, stream, x, w, out);
}

// Round 8
// 133.917 us; speedup vs baseline: 1.4772x; 1.4772x over previous
//
#include <hip/hip_runtime.h>

typedef float v2f __attribute__((ext_vector_type(2)));
typedef float v4f __attribute__((ext_vector_type(4)));

#define EPS 1e-7f
#define SPW 66   // LDS row stride in v2f: 528 B = 33*16 (even pairs stay b128-aligned)

// mantissa_map: (|v|+eps) -> mantissa m in [1,2); result = m>=1.5 ? m/2 : m  -> [0.75,1.5)
__device__ __forceinline__ float mant_map(float v) {
    float a = fabsf(v) + EPS;
    unsigned int bi = __float_as_uint(a);
    float m = __uint_as_float((bi & 0x007FFFFFu) | 0x3F800000u);
    return (m >= 1.5f) ? 0.5f * m : m;
}

// R8: 4-wide columns to halve LDS bytes/output. Grid (192,4,7), block (16,4)
// = 64 thr = 1 wave. Block (c,b,z): output rows y0=8z..y0+7 of plane (b,c).
// Thread (lxc<14, ty): out cols 4lxc..4lxc+3, out rows 2ty, 2ty+1 (2-row
// register rotation over 8 LDS rows: 5 ds_read_b128 per row for 4 cols,
// vs R6's 4 per row for 2 cols).
// out = sum_taps u*B + v*C, u=x, v=x/M1, B=w/M2, C=B*(M2-1).
//
// Model (R0..R7): kernel time ~ 2.35x per-CU LDS-pipe cycles in every healthy
// variant; VGPR allocator hard-caps at 84 (6 waves/SIMD) and scratches above
// it (R2/R3/R7). R8 live set ~80: 2 row-bufs (40) + acc (16) + wt (14).
__global__ __launch_bounds__(64, 4) void wconv_kernel(const float* __restrict__ x,
                                                      const float* __restrict__ w,
                                                      float* __restrict__ out) {
    __shared__ v2f sp[14][SPW];  // LDS row r = input row y0-3+r; pair k = input col k-3
    __shared__ v2f swt[49];      // {B, C} per tap

    const int lx = threadIdx.x;   // 0..15 (col quad; compute clamped to 13)
    const int ty = threadIdx.y;   // 0..3  (out-row pair)
    const int tid = ty * 16 + lx; // 0..63
    const int c = blockIdx.x;
    const int b = blockIdx.y;
    const int y0 = blockIdx.z * 8;

    const long plane = (long)(b * 192 + c) * 3136;
    const float* xp = x + plane;

    // --- fused weight prep ---
    if (tid < 49) {
        float wv = w[c * 49 + tid];
        float M2 = mant_map(wv);
        float B = wv / M2;
        swt[tid] = (v2f){B, B * (M2 - 1.0f)};
    }

    // --- side halo zero: pairs 0,1,2 (cols -3..-1) and 59,60,61 (cols 56..58) ---
    for (int t = tid; t < 84; t += 64) {
        int r = t / 6, k = t % 6;
        int col = (k < 3) ? k : 56 + k;
        sp[r][col] = (v2f){0.f, 0.f};
    }

    // --- interior staging: 14 rows x 14 quads = 196 tasks over 64 threads.
    // Rows outside the image (z=0: g<0, z=6: g>55) stage zeros. Loads first. ---
    {
        const int t0 = tid, t1 = tid + 64, t2 = tid + 128, t3 = tid + 192;
        const int r0 = t0 / 14, q0 = t0 % 14, g0 = y0 - 3 + r0;
        const int r1 = t1 / 14, q1 = t1 % 14, g1 = y0 - 3 + r1;
        const int r2 = t2 / 14, q2 = t2 % 14, g2 = y0 - 3 + r2;
        const int r3 = t3 / 14, q3 = t3 % 14, g3 = y0 - 3 + r3;

        v4f z4 = (v4f){0.f, 0.f, 0.f, 0.f};
        v4f u0 = z4, u1 = z4, u2 = z4, u3 = z4;
        if (g0 >= 0 && g0 < 56) u0 = *(const v4f*)(xp + g0 * 56 + q0 * 4);
        if (g1 >= 0 && g1 < 56) u1 = *(const v4f*)(xp + g1 * 56 + q1 * 4);
        if (g2 >= 0 && g2 < 56) u2 = *(const v4f*)(xp + g2 * 56 + q2 * 4);
        if (tid < 4 && g3 >= 0 && g3 < 56) u3 = *(const v4f*)(xp + g3 * 56 + q3 * 4);

        auto stage = [&](int r, int q, v4f u4) {
            v2f* dst = &sp[r][3 + q * 4];     // pairs 3+4q..6+4q = input cols 4q..4q+3
            dst[0] = (v2f){u4.x, u4.x * __builtin_amdgcn_rcpf(mant_map(u4.x))};
            dst[1] = (v2f){u4.y, u4.y * __builtin_amdgcn_rcpf(mant_map(u4.y))};
            dst[2] = (v2f){u4.z, u4.z * __builtin_amdgcn_rcpf(mant_map(u4.z))};
            dst[3] = (v2f){u4.w, u4.w * __builtin_amdgcn_rcpf(mant_map(u4.w))};
        };
        stage(r0, q0, u0);
        stage(r1, q1, u1);
        stage(r2, q2, u2);
        if (tid < 4) stage(r3, q3, u3);
    }
    __syncthreads();   // 1-wave block: local waitcnt, no cross-wave lockstep

    // --- compute: wave-uniform body (lanes 14,15 duplicate lane 13) ---
    {
        const int lxc = (lx < 14) ? lx : 13;
        const int p0 = lxc * 4;          // window base pair; window pairs p0..p0+9
        const int rb = ty * 2;           // out-row base; LDS rows rb..rb+7

        // row buffer: pairs p0..p0+9 of LDS row R as 5 v4f (5x ds_read_b128)
#define LOADQ(Q, R)                                                     \
        {                                                               \
            const v4f* s_ = (const v4f*)&sp[(R)][p0];                   \
            Q[0] = s_[0]; Q[1] = s_[1]; Q[2] = s_[2]; Q[3] = s_[3]; Q[4] = s_[4]; \
        }
        // window pair P of buffer Q as v2f (P compile-time)
#define PAIR(Q, P) ((P) & 1 ? (v2f){Q[(P) >> 1].z, Q[(P) >> 1].w}       \
                            : (v2f){Q[(P) >> 1].x, Q[(P) >> 1].y})
        // phase: weight row I; out row rb+0 from buffer QA, rb+1 from QB
#define PHASE(I, QA, QB)                                                \
        {                                                               \
            v2f wt_[7];                                                 \
            _Pragma("unroll")                                           \
            for (int j = 0; j < 7; ++j) wt_[j] = swt[(I) * 7 + j];      \
            _Pragma("unroll")                                           \
            for (int k = 0; k < 4; ++k) {                               \
                _Pragma("unroll")                                       \
                for (int j = 0; j < 7; ++j) {                           \
                    a0[k] += PAIR(QA, k + j) * wt_[j];                  \
                    a1[k] += PAIR(QB, k + j) * wt_[j];                  \
                }                                                       \
            }                                                           \
        }

        v4f QA[5], QB[5];
        v2f a0[4], a1[4];
        #pragma unroll
        for (int k = 0; k < 4; ++k) { a0[k] = (v2f){0.f, 0.f}; a1[k] = (v2f){0.f, 0.f}; }

        LOADQ(QA, rb + 0)
        LOADQ(QB, rb + 1)
        PHASE(0, QA, QB)  LOADQ(QA, rb + 2)   // rb+0 done with row rb+0
        PHASE(1, QB, QA)  LOADQ(QB, rb + 3)
        PHASE(2, QA, QB)  LOADQ(QA, rb + 4)
        PHASE(3, QB, QA)  LOADQ(QB, rb + 5)
        PHASE(4, QA, QB)  LOADQ(QA, rb + 6)
        PHASE(5, QB, QA)  LOADQ(QB, rb + 7)
        PHASE(6, QA, QB)
#undef PHASE
#undef PAIR
#undef LOADQ

        // --- store: the only divergent region ---
        if (lx < 14) {
            v4f o0 = (v4f){a0[0].x + a0[0].y, a0[1].x + a0[1].y,
                           a0[2].x + a0[2].y, a0[3].x + a0[3].y};
            v4f o1 = (v4f){a1[0].x + a1[0].y, a1[1].x + a1[1].y,
                           a1[2].x + a1[2].y, a1[3].x + a1[3].y};
            *(v4f*)&out[plane + (y0 + rb)     * 56 + p0] = o0;
            *(v4f*)&out[plane + (y0 + rb + 1) * 56 + p0] = o1;
        }
    }
}

extern "C" void kernel_launch(void* const* d_in, const int* in_sizes, int n_in,
                              void* d_out, int out_size, void* d_ws, size_t ws_size,
                              hipStream_t stream) {
    const float* x = (const float*)d_in[0];   // (4,192,56,56) fp32
    const float* w = (const float*)d_in[1];   // (192,1,7,7) fp32
    float* out = (float*)d_out;

    hipLaunchKernelGGL(wconv_kernel, dim3(192, 4, 7), dim3(16, 4), 0, stream, x, w, out);
}

// Round 9
// 77.028 us; speedup vs baseline: 2.5682x; 1.7386x over previous
//
#include <hip/hip_runtime.h>

typedef float v2f __attribute__((ext_vector_type(2)));
typedef float v4f __attribute__((ext_vector_type(4)));

#define EPS 1e-7f
#define SPW 66   // LDS row stride in v2f: 528 B = 33*16 (even pairs stay b128-aligned)

// mantissa_map: (|v|+eps) -> mantissa m in [1,2); result = m>=1.5 ? m/2 : m  -> [0.75,1.5)
__device__ __forceinline__ float mant_map(float v) {
    float a = fabsf(v) + EPS;
    unsigned int bi = __float_as_uint(a);
    float m = __uint_as_float((bi & 0x007FFFFFu) | 0x3F800000u);
    return (m >= 1.5f) ? 0.5f * m : m;
}

// R9: R8's low-amplification tile (2 out rows x 4 cols = 5 ds_read_b128 per
// output) restructured to fit the ~64-VGPR wall the allocator enforces
// (R2/R3/R7/R8 all spilled above it). Single row buffer Q (20 regs) + current
// weight row in VGPRs (14) + PREVIOUS weight row parked in SGPRs via
// readfirstlane (weights are wave-uniform; compute body is full-exec per R5).
// Step i: LDS row rb+i serves out-row rb (wrow i, pk_fma w/ VGPR weights) and
// out-row rb+1 (wrow i-1, scalar v_fma w/ SGPR weights). Live ~58 VGPRs.
// Grid (192,4,7), block (16,4) = 1 wave. out = sum u*B + v*C.
__global__ __launch_bounds__(64) void wconv_kernel(const float* __restrict__ x,
                                                   const float* __restrict__ w,
                                                   float* __restrict__ out) {
    __shared__ v2f sp[14][SPW];  // LDS row r = input row y0-3+r; pair k = input col k-3
    __shared__ v2f swt[49];      // {B, C} per tap

    const int lx = threadIdx.x;   // 0..15 (col quad; compute clamped to 13)
    const int ty = threadIdx.y;   // 0..3  (out-row pair)
    const int tid = ty * 16 + lx; // 0..63
    const int c = blockIdx.x;
    const int b = blockIdx.y;
    const int y0 = blockIdx.z * 8;

    const long plane = (long)(b * 192 + c) * 3136;
    const float* xp = x + plane;

    // --- fused weight prep ---
    if (tid < 49) {
        float wv = w[c * 49 + tid];
        float M2 = mant_map(wv);
        float B = wv / M2;
        swt[tid] = (v2f){B, B * (M2 - 1.0f)};
    }

    // --- side halo zero: pairs 0,1,2 (cols -3..-1) and 59,60,61 (cols 56..58) ---
    for (int t = tid; t < 84; t += 64) {
        int r = t / 6, k = t % 6;
        int col = (k < 3) ? k : 56 + k;
        sp[r][col] = (v2f){0.f, 0.f};
    }

    // --- interior staging: 14 rows x 14 quads = 196 tasks over 64 threads.
    // Rows outside the image (z=0: g<0, z=6: g>55) stage zeros. Loads first. ---
    {
        const int t0 = tid, t1 = tid + 64, t2 = tid + 128, t3 = tid + 192;
        const int r0 = t0 / 14, q0 = t0 % 14, g0 = y0 - 3 + r0;
        const int r1 = t1 / 14, q1 = t1 % 14, g1 = y0 - 3 + r1;
        const int r2 = t2 / 14, q2 = t2 % 14, g2 = y0 - 3 + r2;
        const int r3 = t3 / 14, q3 = t3 % 14, g3 = y0 - 3 + r3;

        v4f z4 = (v4f){0.f, 0.f, 0.f, 0.f};
        v4f u0 = z4, u1 = z4, u2 = z4, u3 = z4;
        if (g0 >= 0 && g0 < 56) u0 = *(const v4f*)(xp + g0 * 56 + q0 * 4);
        if (g1 >= 0 && g1 < 56) u1 = *(const v4f*)(xp + g1 * 56 + q1 * 4);
        if (g2 >= 0 && g2 < 56) u2 = *(const v4f*)(xp + g2 * 56 + q2 * 4);
        if (tid < 4 && g3 >= 0 && g3 < 56) u3 = *(const v4f*)(xp + g3 * 56 + q3 * 4);

        auto stage = [&](int r, int q, v4f u4) {
            v2f* dst = &sp[r][3 + q * 4];     // pairs 3+4q..6+4q = input cols 4q..4q+3
            dst[0] = (v2f){u4.x, u4.x * __builtin_amdgcn_rcpf(mant_map(u4.x))};
            dst[1] = (v2f){u4.y, u4.y * __builtin_amdgcn_rcpf(mant_map(u4.y))};
            dst[2] = (v2f){u4.z, u4.z * __builtin_amdgcn_rcpf(mant_map(u4.z))};
            dst[3] = (v2f){u4.w, u4.w * __builtin_amdgcn_rcpf(mant_map(u4.w))};
        };
        stage(r0, q0, u0);
        stage(r1, q1, u1);
        stage(r2, q2, u2);
        if (tid < 4) stage(r3, q3, u3);
    }
    __syncthreads();   // 1-wave block: local waitcnt, no cross-wave lockstep

    // --- compute: wave-uniform body (lanes 14,15 duplicate lane 13) ---
    {
        const int lxc = (lx < 14) ? lx : 13;
        const int p0 = lxc * 4;          // window base pair; window pairs p0..p0+9
        const int rb = ty * 2;           // out-row base; LDS rows rb..rb+7

        v4f Q[5];                        // current LDS row, pairs p0..p0+9
        v2f wc[7];                       // current weight row {B,C} (VGPR)
        float pB[7], pC[7];              // previous weight row (SGPR via readfirstlane)
        v2f a0[4], a1[4];                // out rows rb, rb+1 x 4 cols; {sum u*B, sum v*C}
        #pragma unroll
        for (int k = 0; k < 4; ++k) { a0[k] = (v2f){0.f, 0.f}; a1[k] = (v2f){0.f, 0.f}; }

        // window pair p of Q (p compile-time): even p = low half, odd = high half
#define PU(p) ((p) & 1 ? Q[(p) >> 1].z : Q[(p) >> 1].x)
#define PV(p) ((p) & 1 ? Q[(p) >> 1].w : Q[(p) >> 1].y)
#define RFL(f) __uint_as_float(__builtin_amdgcn_readfirstlane(__float_as_uint(f)))

        // step I (0..7): LDS row rb+I -> out rb (wrow I, cur) + out rb+1 (wrow I-1, prev)
#define STEP(I)                                                         \
        {                                                               \
            { const v4f* s_ = (const v4f*)&sp[rb + (I)][p0];            \
              Q[0]=s_[0]; Q[1]=s_[1]; Q[2]=s_[2]; Q[3]=s_[3]; Q[4]=s_[4]; } \
            if ((I) < 7) {                                              \
                _Pragma("unroll")                                       \
                for (int j = 0; j < 7; ++j) wc[j] = swt[(I) * 7 + j];   \
            }                                                           \
            if ((I) >= 1) {   /* prev row: scalar FMA, SGPR weights */  \
                _Pragma("unroll")                                       \
                for (int k = 0; k < 4; ++k)                             \
                    _Pragma("unroll")                                   \
                    for (int j = 0; j < 7; ++j) {                       \
                        a1[k].x = fmaf(PU(k + j), pB[j], a1[k].x);      \
                        a1[k].y = fmaf(PV(k + j), pC[j], a1[k].y);      \
                    }                                                   \
            }                                                           \
            if ((I) <= 6) {   /* cur row: packed FMA, VGPR weights */   \
                _Pragma("unroll")                                       \
                for (int k = 0; k < 4; ++k)                             \
                    _Pragma("unroll")                                   \
                    for (int j = 0; j < 7; ++j) {                       \
                        v2f w_ = wc[j];                                 \
                        a0[k] += (v2f){PU(k + j), PV(k + j)} * w_;      \
                    }                                                   \
            }                                                           \
            if ((I) < 7) {    /* park wrow I in SGPRs for step I+1 */   \
                _Pragma("unroll")                                       \
                for (int j = 0; j < 7; ++j) {                           \
                    pB[j] = RFL(wc[j].x);                               \
                    pC[j] = RFL(wc[j].y);                               \
                }                                                       \
            }                                                           \
        }

        STEP(0) STEP(1) STEP(2) STEP(3) STEP(4) STEP(5) STEP(6) STEP(7)
#undef STEP
#undef RFL
#undef PV
#undef PU

        // --- store: the only divergent region ---
        if (lx < 14) {
            v4f o0 = (v4f){a0[0].x + a0[0].y, a0[1].x + a0[1].y,
                           a0[2].x + a0[2].y, a0[3].x + a0[3].y};
            v4f o1 = (v4f){a1[0].x + a1[0].y, a1[1].x + a1[1].y,
                           a1[2].x + a1[2].y, a1[3].x + a1[3].y};
            *(v4f*)&out[plane + (y0 + rb)     * 56 + p0] = o0;
            *(v4f*)&out[plane + (y0 + rb + 1) * 56 + p0] = o1;
        }
    }
}

extern "C" void kernel_launch(void* const* d_in, const int* in_sizes, int n_in,
                              void* d_out, int out_size, void* d_ws, size_t ws_size,
                              hipStream_t stream) {
    const float* x = (const float*)d_in[0];   // (4,192,56,56) fp32
    const float* w = (const float*)d_in[1];   // (192,1,7,7) fp32
    float* out = (float*)d_out;

    hipLaunchKernelGGL(wconv_kernel, dim3(192, 4, 7), dim3(16, 4), 0, stream, x, w, out);
}